// Round 1
// 676.238 us; speedup vs baseline: 1.3393x; 1.3393x over previous
//
#include <hip/hip_runtime.h>

typedef short s8v __attribute__((ext_vector_type(8)));
typedef short s4v __attribute__((ext_vector_type(4)));
typedef float f4v __attribute__((ext_vector_type(4)));

#define HW     200704      // 448*448
#define NCH    192
#define PT     64          // pixels per tile
#define CMP    68          // channel-major LDS pitch (elements)
#define PMP    200         // pixel-major LDS pitch (elements)
#define GRID   512
#define NTILES 3136        // HW/PT

__device__ __forceinline__ float b2f(unsigned short u){
    unsigned int i = ((unsigned int)u) << 16; float f;
    __builtin_memcpy(&f, &i, 4); return f;
}
__device__ __forceinline__ unsigned short f2b(float f){
    unsigned int i; __builtin_memcpy(&i, &f, 4);
    i += 0x7FFFu + ((i >> 16) & 1u);
    return (unsigned short)(i >> 16);
}
// octet swizzle for pixel-major buffers: injective bank mapping
__device__ __forceinline__ int swz(int oct, int p){
    return (oct & ~7) | ((oct + 2*(p & 7)) & 7);
}

// ============================ prep: zero accumulators + tickets + weights fp32->bf16 ============================
// wbf layout (u16): pre_w @0 (36864), qkv_w @36864 (110592), proj_w @147456 (36864)
__global__ void gsa_prep(const float* __restrict__ pre_w, const float* __restrict__ qkv_w,
                         const float* __restrict__ proj_w, unsigned short* __restrict__ wbf,
                         float* __restrict__ accs, unsigned int* __restrict__ ctr)
{
    int i = blockIdx.x*256 + threadIdx.x;
    if (i < 2)      ctr[i] = 0u;
    if (i < 6528)   accs[i] = 0.f;
    if (i < 36864)  wbf[i]           = f2b(pre_w[i]);
    if (i < 110592) wbf[36864 + i]   = f2b(qkv_w[i]);
    if (i < 36864)  wbf[147456 + i]  = f2b(proj_w[i]);
}

// ============================ K1 ============================
// LN + pre GEMM + qkv GEMM + Gram/sumsq + v (bf16, tile-interleaved) -> d_out
// 384 threads = 6 waves/block; 2 blocks/CU -> 12 waves/CU (was 8).
__global__ __launch_bounds__(384, 3) void gsa_k1(
    const float* __restrict__ x,
    const float* __restrict__ lng,
    const float* __restrict__ lnb,
    const unsigned short* __restrict__ pre_wb,
    const float* __restrict__ pre_b,
    const unsigned short* __restrict__ qkv_wb,
    unsigned short* __restrict__ v_out,      // u16 view of d_out
    float* __restrict__ gram_red,
    float* __restrict__ sq_red,
    unsigned int* __restrict__ ctr)
{
    __shared__ __align__(16) unsigned char smem[26112*2 + 25600 + 1536];
    __shared__ int t_sh;
    unsigned short* bufA  = (unsigned short*)smem;              // cm [192][68]: x(bf16) -> q -> v
    unsigned short* bufP1 = (unsigned short*)(smem + 26112);    // pm xn -> cm k
    unsigned short* bufP2 = (unsigned short*)(smem + 2*26112);  // pm y (stats alias before y)
    float* sq_lds = (float*)(smem + 2*26112 + 25600);           // [384]
    float* stats  = (float*)bufP2;

    const int tid  = threadIdx.x;
    const int wid  = tid >> 6;     // 0..5
    const int lane = tid & 63;
    const int l15  = lane & 15;
    const int quad = lane >> 4;

    f4v gacc[4];
    #pragma unroll
    for (int g = 0; g < 4; ++g) gacc[g] = (f4v){0.f, 0.f, 0.f, 0.f};
    sq_lds[tid] = 0.f;

    auto gemm2 = [&](int co, f4v (&acc)[2][4]) {
        #pragma unroll
        for (int j = 0; j < 2; ++j)
            #pragma unroll
            for (int nt = 0; nt < 4; ++nt) acc[j][nt] = (f4v){0.f,0.f,0.f,0.f};
        #pragma unroll
        for (int ks = 0; ks < 6; ++ks) {
            s8v a[2];
            #pragma unroll
            for (int j = 0; j < 2; ++j)
                a[j] = *(const s8v*)(qkv_wb + (size_t)(co*NCH + wid*32 + j*16 + l15)*NCH + ks*32 + quad*8);
            #pragma unroll
            for (int nt = 0; nt < 4; ++nt) {
                int p = nt*16 + l15;
                s8v b = *(const s8v*)(bufP2 + p*PMP + swz(ks*4 + quad, p)*8);
                #pragma unroll
                for (int j = 0; j < 2; ++j)
                    acc[j][nt] = __builtin_amdgcn_mfma_f32_16x16x32_bf16(a[j], b, acc[j][nt], 0, 0, 0);
            }
        }
    };

    for (;;) {
        __syncthreads();   // S0: prev-tile bufA reads + t_sh reads done
        if (tid == 0) t_sh = atomicAdd(ctr, 1u);
        __syncthreads();
        const int t = t_sh;
        if (t >= NTILES) break;
        const int p0 = t * PT;

        // ---- phase A: stage x tile fp32 -> bf16, channel-major ----
        {
            const int c0 = tid >> 3, oct = tid & 7;   // c0 in [0,48)
            #pragma unroll
            for (int pass = 0; pass < 4; ++pass) {
                int c = pass*48 + c0;
                const float* gp = x + (size_t)c*HW + p0 + oct*8;
                f4v f0 = *(const f4v*)(gp);
                f4v f1 = *(const f4v*)(gp + 4);
                s8v w;
                #pragma unroll
                for (int r = 0; r < 4; ++r) { w[r] = (short)f2b(f0[r]); w[4+r] = (short)f2b(f1[r]); }
                *(s8v*)(bufA + c*CMP + oct*8) = w;
            }
        }
        __syncthreads();   // S1

        // ---- phase B: per-pixel mean/var over 192 channels ----
        {
            const int p = lane, g = wid;
            float s1 = 0.f, s2 = 0.f;
            #pragma unroll
            for (int i = 0; i < 32; ++i) {
                float v = b2f(bufA[(g*32 + i)*CMP + p]);
                s1 += v; s2 += v*v;
            }
            stats[g*64 + p]       = s1;
            stats[384 + g*64 + p] = s2;
        }
        __syncthreads();   // S2
        if (tid < 64) {
            float s1 = 0.f, s2 = 0.f;
            #pragma unroll
            for (int g = 0; g < 6; ++g) { s1 += stats[g*64 + tid]; s2 += stats[384 + g*64 + tid]; }
            float mu  = s1 * (1.f/192.f);
            float var = s2 * (1.f/192.f) - mu*mu;
            stats[768 + tid] = mu;
            stats[832 + tid] = rsqrtf(fmaxf(var, 0.f) + 1e-5f);
        }
        __syncthreads();   // S3

        // ---- phase C: normalize + transpose -> pm xn (bufP1, swizzled) ----
        {
            const int p = lane, g = wid;
            const float mu = stats[768 + p], is = stats[832 + p];
            #pragma unroll
            for (int oo = 0; oo < 4; ++oo) {
                s8v w;
                #pragma unroll
                for (int j = 0; j < 8; ++j) {
                    int c = g*32 + oo*8 + j;
                    float v = (b2f(bufA[c*CMP + p]) - mu) * is;
                    v = v * lng[c] + lnb[c];
                    w[j] = (short)f2b(v);
                }
                int oct = g*4 + oo;
                *(s8v*)(bufP1 + p*PMP + swz(oct, p)*8) = w;
            }
        }
        __syncthreads();   // S4

        // ---- GEMM1: y = pre_w * xn + pre_b -> bufP2 (pm, swizzled) ----
        {
            f4v acc[2][4];
            #pragma unroll
            for (int j = 0; j < 2; ++j)
                #pragma unroll
                for (int nt = 0; nt < 4; ++nt) acc[j][nt] = (f4v){0.f,0.f,0.f,0.f};
            #pragma unroll
            for (int ks = 0; ks < 6; ++ks) {
                s8v a[2];
                #pragma unroll
                for (int j = 0; j < 2; ++j)
                    a[j] = *(const s8v*)(pre_wb + (size_t)((wid*2 + j)*16 + l15)*NCH + ks*32 + quad*8);
                #pragma unroll
                for (int nt = 0; nt < 4; ++nt) {
                    int p = nt*16 + l15;
                    s8v b = *(const s8v*)(bufP1 + p*PMP + swz(ks*4 + quad, p)*8);
                    #pragma unroll
                    for (int j = 0; j < 2; ++j)
                        acc[j][nt] = __builtin_amdgcn_mfma_f32_16x16x32_bf16(a[j], b, acc[j][nt], 0, 0, 0);
                }
            }
            #pragma unroll
            for (int j = 0; j < 2; ++j) {
                int c0 = (wid*2 + j)*16 + quad*4;
                f4v pb4 = *(const f4v*)(pre_b + c0);
                int oct = c0 >> 3, half = (c0 >> 2) & 1;
                #pragma unroll
                for (int nt = 0; nt < 4; ++nt) {
                    int p = nt*16 + l15;
                    s4v w;
                    #pragma unroll
                    for (int r = 0; r < 4; ++r)
                        w[r] = (short)f2b(acc[j][nt][r] + pb4[r]);
                    *(s4v*)(bufP2 + p*PMP + swz(oct, p)*8 + half*4) = w;
                }
            }
        }
        __syncthreads();   // S5

        // ---- GEMM2 q & k ----
        {
            f4v acc[2][4];
            gemm2(0, acc);   // q -> bufA (cm)
            #pragma unroll
            for (int j = 0; j < 2; ++j)
                #pragma unroll
                for (int nt = 0; nt < 4; ++nt) {
                    int p = nt*16 + l15;
                    #pragma unroll
                    for (int r = 0; r < 4; ++r) {
                        int c = wid*32 + j*16 + quad*4 + r;
                        bufA[c*CMP + p] = f2b(acc[j][nt][r]);
                    }
                }
            gemm2(1, acc);   // k -> bufP1 (cm)
            #pragma unroll
            for (int j = 0; j < 2; ++j)
                #pragma unroll
                for (int nt = 0; nt < 4; ++nt) {
                    int p = nt*16 + l15;
                    #pragma unroll
                    for (int r = 0; r < 4; ++r) {
                        int c = wid*32 + j*16 + quad*4 + r;
                        bufP1[c*CMP + p] = f2b(acc[j][nt][r]);
                    }
                }
        }
        __syncthreads();   // S6

        // ---- sumsq of q,k rows: row-wise vector reads (replaces per-element bpermute chains) ----
        {
            const unsigned short* src = (wid < 3) ? (bufA + tid*CMP) : (bufP1 + (tid - 192)*CMP);
            float s = 0.f;
            #pragma unroll
            for (int o = 0; o < 8; ++o) {
                s4v lo = *(const s4v*)(src + o*8);
                s4v hi = *(const s4v*)(src + o*8 + 4);
                #pragma unroll
                for (int e = 0; e < 4; ++e) {
                    float a = b2f((unsigned short)lo[e]);
                    float b = b2f((unsigned short)hi[e]);
                    s += a*a + b*b;
                }
            }
            sq_lds[tid] += s;
        }

        // ---- Gram accumulate (per head, across tiles) ----
        #pragma unroll
        for (int g = 0; g < 4; ++g) {
            int gt = wid*4 + g, h = gt >> 2, dm = (gt >> 1) & 1, em = gt & 1;
            const unsigned short* qrow = bufA  + (h*32 + dm*16 + l15)*CMP;
            const unsigned short* krow = bufP1 + (h*32 + em*16 + l15)*CMP;
            #pragma unroll
            for (int ks = 0; ks < 2; ++ks) {
                int off = ks*32 + quad*8;
                s4v alo = *(const s4v*)(qrow + off), ahi = *(const s4v*)(qrow + off + 4);
                s4v blo = *(const s4v*)(krow + off), bhi = *(const s4v*)(krow + off + 4);
                s8v a = __builtin_shufflevector(alo, ahi, 0,1,2,3,4,5,6,7);
                s8v b = __builtin_shufflevector(blo, bhi, 0,1,2,3,4,5,6,7);
                gacc[g] = __builtin_amdgcn_mfma_f32_16x16x32_bf16(a, b, gacc[g], 0, 0, 0);
            }
        }

        // ---- GEMM2 v chunk -> bufA -> interleaved bf16 store into d_out ----
        {
            f4v acc[2][4];
            gemm2(2, acc);
            __syncthreads();   // S7: gram/sumsq reads of bufA done
            #pragma unroll
            for (int j = 0; j < 2; ++j)
                #pragma unroll
                for (int nt = 0; nt < 4; ++nt) {
                    int p = nt*16 + l15;
                    #pragma unroll
                    for (int r = 0; r < 4; ++r) {
                        int c = wid*32 + j*16 + quad*4 + r;
                        bufA[c*CMP + p] = f2b(acc[j][nt][r]);
                    }
                }
        }
        __syncthreads();   // S8
        {
            const int c0 = tid >> 3, oct = tid & 7;
            #pragma unroll
            for (int pass = 0; pass < 4; ++pass) {
                int c = pass*48 + c0;
                s4v lo = *(const s4v*)(bufA + c*CMP + oct*8);
                s4v hi = *(const s4v*)(bufA + c*CMP + oct*8 + 4);
                s8v w = __builtin_shufflevector(lo, hi, 0,1,2,3,4,5,6,7);
                // v tile t lives in the u16 span that K3's tile-t iteration overwrites:
                *(s8v*)(v_out + 2*((size_t)c*HW + p0) + oct*8) = w;
            }
        }
    }

    #pragma unroll
    for (int g = 0; g < 4; ++g) {
        int gt = wid*4 + g, h = gt >> 2, dm = (gt >> 1) & 1, em = gt & 1;
        #pragma unroll
        for (int r = 0; r < 4; ++r) {
            int d = dm*16 + quad*4 + r, e = em*16 + l15;
            atomicAdd(&gram_red[h*1024 + d*32 + e], gacc[g][r]);
        }
    }
    atomicAdd(&sq_red[tid], sq_lds[tid]);
}

// ============================ K2: attn normalize + mn_w + gating -> gm (bf16) ============================
__global__ void gsa_k2(const float* __restrict__ gram_red, const float* __restrict__ sq_red,
                       const float* __restrict__ mn_w, const float* __restrict__ gating,
                       unsigned short* __restrict__ gm_out)
{
    __shared__ float attn[6144];
    __shared__ float mw[2048];
    __shared__ float inv[384];
    const int tid = threadIdx.x;
    for (int i = tid; i < 384; i += 256)
        inv[i] = 1.f / fmaxf(sqrtf(fmaxf(sq_red[i], 0.f)), 1e-12f);
    for (int i = tid; i < 2048; i += 256) mw[i] = mn_w[i];
    __syncthreads();
    for (int i = tid; i < 6144; i += 256) {
        int h = i >> 10, d = (i >> 5) & 31, e = i & 31;
        attn[i] = gram_red[i] * inv[h*32 + d] * inv[192 + h*32 + e];
    }
    __syncthreads();
    if (tid < 192) {
        int h = tid >> 5, d = tid & 31;
        float g1 = gating[h], g2 = gating[6 + h];
        const float* ar = attn + h*1024 + d*32;
        for (int e = 0; e < 32; ++e) {
            float m = 0.f, n = 0.f;
            for (int c2 = 0; c2 < 32; ++c2) {
                m += ar[c2] * mw[e*32 + c2];
                n += ar[c2] * mw[(e + 32)*32 + c2];
            }
            gm_out[h*1024 + d*32 + e] = f2b(g1*m + g2*n);
        }
    }
}

// ============================ K3: mi = gm*illu, softmax(mi*v), proj + x ============================
__global__ __launch_bounds__(384, 3) void gsa_k3(
    const float* __restrict__ cond,
    const float* __restrict__ x,
    const unsigned short* __restrict__ gm,
    const unsigned short* __restrict__ proj_wb,
    const unsigned short* v_in,     // u16 view of d_out (tile-interleaved v)
    float* out,                     // fp32 view of d_out
    unsigned int* __restrict__ ctr)
{
    __shared__ __align__(16) unsigned char smem[26112 + 25600 + 25600];
    __shared__ int t_sh;
    unsigned short* bufA = (unsigned short*)smem;                     // cm: cond -> v -> proj bounce
    unsigned short* bufB = (unsigned short*)(smem + 26112);           // pm illu (swizzled)
    unsigned short* bufC = (unsigned short*)(smem + 26112 + 25600);   // pm sm (swizzled)

    const int tid  = threadIdx.x;
    const int wid  = tid >> 6;     // 0..5
    const int lane = tid & 63;
    const int l15  = lane & 15;
    const int quad = lane >> 4;

    for (;;) {
        __syncthreads();   // prev-iter bufA reads + t_sh reads done
        if (tid == 0) t_sh = atomicAdd(ctr + 1, 1u);
        __syncthreads();
        const int t = t_sh;
        if (t >= NTILES) break;
        const int p0 = t * PT;

        // phase A: cond fp32 -> bf16 cm
        {
            const int c0 = tid >> 3, oct = tid & 7;
            #pragma unroll
            for (int pass = 0; pass < 4; ++pass) {
                int c = pass*48 + c0;
                const float* gp = cond + (size_t)c*HW + p0 + oct*8;
                f4v f0 = *(const f4v*)(gp);
                f4v f1 = *(const f4v*)(gp + 4);
                s8v w;
                #pragma unroll
                for (int r = 0; r < 4; ++r) { w[r] = (short)f2b(f0[r]); w[4+r] = (short)f2b(f1[r]); }
                *(s8v*)(bufA + c*CMP + oct*8) = w;
            }
        }
        __syncthreads();
        // transpose -> pm illu (swizzled)
        {
            const int p = lane, g = wid;
            #pragma unroll
            for (int oo = 0; oo < 4; ++oo) {
                int oct = g*4 + oo;
                s8v w;
                #pragma unroll
                for (int j = 0; j < 8; ++j)
                    w[j] = (short)bufA[(oct*8 + j)*CMP + p];
                *(s8v*)(bufB + p*PMP + swz(oct, p)*8) = w;
            }
        }
        __syncthreads();
        // stage v (interleaved bf16 in d_out) -> bufA cm
        {
            const int c0 = tid >> 3, oct = tid & 7;
            #pragma unroll
            for (int pass = 0; pass < 4; ++pass) {
                int c = pass*48 + c0;
                s8v vv = *(const s8v*)(v_in + 2*((size_t)c*HW + p0) + oct*8);
                s4v lo = __builtin_shufflevector(vv, vv, 0,1,2,3);
                s4v hi = __builtin_shufflevector(vv, vv, 4,5,6,7);
                *(s4v*)(bufA + c*CMP + oct*8)     = lo;
                *(s4v*)(bufA + c*CMP + oct*8 + 4) = hi;
            }
        }
        __syncthreads();

        // mi MFMA + *v + softmax over head-dim -> bufC
        {
            #pragma unroll
            for (int j = 0; j < 4; ++j) {
                int pr = wid*4 + j, h = pr >> 2, nt = pr & 3;
                int p = nt*16 + l15;
                s8v a0 = *(const s8v*)(gm + h*1024 + l15*32 + quad*8);
                s8v a1 = *(const s8v*)(gm + h*1024 + (16 + l15)*32 + quad*8);
                s8v b  = *(const s8v*)(bufB + p*PMP + swz(h*4 + quad, p)*8);
                f4v z = (f4v){0.f,0.f,0.f,0.f};
                f4v m0 = __builtin_amdgcn_mfma_f32_16x16x32_bf16(a0, b, z, 0, 0, 0);
                f4v m1 = __builtin_amdgcn_mfma_f32_16x16x32_bf16(a1, b, z, 0, 0, 0);
                float tv[8];
                #pragma unroll
                for (int r = 0; r < 4; ++r) {
                    tv[r]     = m0[r] * b2f(bufA[(h*32 + quad*4 + r)*CMP + p]);
                    tv[4 + r] = m1[r] * b2f(bufA[(h*32 + 16 + quad*4 + r)*CMP + p]);
                }
                float mx = tv[0];
                #pragma unroll
                for (int r = 1; r < 8; ++r) mx = fmaxf(mx, tv[r]);
                mx = fmaxf(mx, __shfl_xor(mx, 16));
                mx = fmaxf(mx, __shfl_xor(mx, 32));
                float s = 0.f;
                #pragma unroll
                for (int r = 0; r < 8; ++r) { tv[r] = __expf(tv[r] - mx); s += tv[r]; }
                s += __shfl_xor(s, 16);
                s += __shfl_xor(s, 32);
                float is = 1.f / s;
                s4v w0, w1;
                #pragma unroll
                for (int r = 0; r < 4; ++r) {
                    w0[r] = (short)f2b(tv[r] * is);
                    w1[r] = (short)f2b(tv[4 + r] * is);
                }
                int c0 = h*32 + quad*4, c1 = c0 + 16;
                *(s4v*)(bufC + p*PMP + swz(c0 >> 3, p)*8 + ((c0 >> 2) & 1)*4) = w0;
                *(s4v*)(bufC + p*PMP + swz(c1 >> 3, p)*8 + ((c1 >> 2) & 1)*4) = w1;
            }
        }
        __syncthreads();

        // GEMM4: proj_w * sm -> bufA (bf16 bounce)
        {
            f4v acc[2][4];
            #pragma unroll
            for (int j = 0; j < 2; ++j)
                #pragma unroll
                for (int nt = 0; nt < 4; ++nt) acc[j][nt] = (f4v){0.f,0.f,0.f,0.f};
            #pragma unroll
            for (int ks = 0; ks < 6; ++ks) {
                s8v a[2];
                #pragma unroll
                for (int j = 0; j < 2; ++j)
                    a[j] = *(const s8v*)(proj_wb + (size_t)((wid*2 + j)*16 + l15)*NCH + ks*32 + quad*8);
                #pragma unroll
                for (int nt = 0; nt < 4; ++nt) {
                    int p = nt*16 + l15;
                    s8v b = *(const s8v*)(bufC + p*PMP + swz(ks*4 + quad, p)*8);
                    #pragma unroll
                    for (int j = 0; j < 2; ++j)
                        acc[j][nt] = __builtin_amdgcn_mfma_f32_16x16x32_bf16(a[j], b, acc[j][nt], 0, 0, 0);
                }
            }
            __syncthreads();   // mi-phase reads of bufA (v) done
            #pragma unroll
            for (int j = 0; j < 2; ++j)
                #pragma unroll
                for (int nt = 0; nt < 4; ++nt) {
                    int p = nt*16 + l15;
                    #pragma unroll
                    for (int r = 0; r < 4; ++r) {
                        int c = wid*32 + j*16 + quad*4 + r;
                        bufA[c*CMP + p] = f2b(acc[j][nt][r]);
                    }
                }
        }
        __syncthreads();

        // epilogue: out = proj + x (fp32, coalesced float4)
        {
            const int c0 = tid >> 3, oct = tid & 7;
            #pragma unroll
            for (int pass = 0; pass < 4; ++pass) {
                int c = pass*48 + c0;
                const float* xp = x + (size_t)c*HW + p0 + oct*8;
                f4v x0 = *(const f4v*)(xp);
                f4v x1 = *(const f4v*)(xp + 4);
                f4v o0, o1;
                #pragma unroll
                for (int r = 0; r < 4; ++r) {
                    o0[r] = b2f(bufA[c*CMP + oct*8 + r])     + x0[r];
                    o1[r] = b2f(bufA[c*CMP + oct*8 + 4 + r]) + x1[r];
                }
                float* op = out + (size_t)c*HW + p0 + oct*8;
                *(f4v*)(op)     = o0;
                *(f4v*)(op + 4) = o1;
            }
        }
    }
}

// ============================ launch ============================
extern "C" void kernel_launch(void* const* d_in, const int* in_sizes, int n_in,
                              void* d_out, int out_size, void* d_ws, size_t ws_size,
                              hipStream_t stream)
{
    (void)in_sizes; (void)n_in; (void)out_size; (void)ws_size;
    const float* x      = (const float*)d_in[0];
    const float* cond   = (const float*)d_in[1];
    const float* lng    = (const float*)d_in[2];
    const float* lnb    = (const float*)d_in[3];
    const float* pre_w  = (const float*)d_in[4];
    const float* pre_b  = (const float*)d_in[5];
    const float* qkv_w  = (const float*)d_in[6];
    const float* mn_w   = (const float*)d_in[7];
    const float* gating = (const float*)d_in[8];
    const float* proj_w = (const float*)d_in[9];

    // workspace layout:
    //   [0,24576)        gram_red (6144 f32)
    //   [24576,26112)    sq_red   (384 f32)
    //   [26112,38400)    gm       (6144 bf16)
    //   [38400,407040)   wbf: pre_w_bf16 (73728 B) | qkv_w_bf16 (221184 B) | proj_w_bf16 (73728 B)
    //   [407040,407048)  tickets: ctr[0]=K1, ctr[1]=K3
    char* ws = (char*)d_ws;
    float* gram_red = (float*)ws;
    float* sq_red   = (float*)(ws + 24576);
    unsigned short* gm  = (unsigned short*)(ws + 26112);
    unsigned short* wbf = (unsigned short*)(ws + 38400);
    unsigned int* ctr   = (unsigned int*)(ws + 407040);
    unsigned short* pre_wb  = wbf;
    unsigned short* qkv_wb  = wbf + 36864;
    unsigned short* proj_wb = wbf + 147456;

    gsa_prep<<<432,  256, 0, stream>>>(pre_w, qkv_w, proj_w, wbf, gram_red, ctr);
    gsa_k1 <<<GRID,  384, 0, stream>>>(x, lng, lnb, pre_wb, pre_b, qkv_wb,
                                       (unsigned short*)d_out, gram_red, sq_red, ctr);
    gsa_k2 <<<1,     256, 0, stream>>>(gram_red, sq_red, mn_w, gating, gm);
    gsa_k3 <<<GRID,  384, 0, stream>>>(cond, x, gm, proj_wb,
                                       (const unsigned short*)d_out, (float*)d_out, ctr);
}